// Round 1
// baseline (312.003 us; speedup 1.0000x reference)
//
#include <hip/hip_runtime.h>
#include <hip/hip_bf16.h>

// Problem constants
#define BB 32
#define CIN 96
#define TT 288
#define VV 25
#define SS 3
#define COUT 96
#define WSZ 5
#define BN_EPS 1e-5f
#define TV (TT*VV)              // 7200
#define KK 288                  // fused GEMM K = s*96+i
#define XCOLS 64                // XAtile rows allocated (50 used; 64 so junk reads stay in-bounds)

typedef __attribute__((ext_vector_type(8))) short bf16x8;
typedef __attribute__((ext_vector_type(4))) float f32x4;

__device__ __forceinline__ unsigned short f2bf(float f) {
    unsigned u = __float_as_uint(f);
    return (unsigned short)((u + 0x7fffu + ((u >> 16) & 1u)) >> 16);  // RNE
}

// ---------------------------------------------------------------------------
// prep: Wflat[c][k=s*96+i] = bf16(0.2 * conv_w[(s*96+c)*96+i]);   // 1/WSZ folded in!
//       Bfr[f=s*2+nt][lane][j] = B-fragment of A_s for 16x16x32 MFMA
//       zbias[c*25+m] = sum_s cb[s*96+c] * sum_n A[s,n,m];  (UNscaled; ×cnt/5 at use)
//       stats[0..191] = 0.
// ---------------------------------------------------------------------------
__global__ __launch_bounds__(256) void prep(
    const float* __restrict__ conv_w, const float* __restrict__ A,
    const float* __restrict__ cb,
    __hip_bfloat16* __restrict__ Wflat,   // [96][288]
    __hip_bfloat16* __restrict__ Bfr,     // [6][64][8]
    float* __restrict__ zbias,            // [2400]
    float* __restrict__ stats)            // [192]
{
    int id = blockIdx.x*256 + threadIdx.x;
    if (id < 27648) {
        int c = id / KK, k = id - c*KK;
        int s = k / CIN, i = k - s*CIN;
        Wflat[id] = __float2bfloat16(0.2f * conv_w[(s*COUT + c)*CIN + i]);
    } else if (id < 27648 + 3072) {
        int e = id - 27648;               // f*512 + l*8 + j
        int f = e >> 9, rem = e & 511;
        int l = rem >> 3, j = rem & 7;
        int s = f >> 1, nt = f & 1;
        int n = (l >> 4)*8 + j;
        int m = nt*16 + (l & 15);
        float v = (n < VV && m < VV) ? A[(s*VV + n)*VV + m] : 0.0f;
        Bfr[e] = __float2bfloat16(v);
    } else if (id < 27648 + 3072 + 2400) {
        int e = id - 27648 - 3072;
        int c = e / VV, m = e - c*VV;
        float v = 0.f;
        #pragma unroll
        for (int s = 0; s < SS; ++s) {
            float sa = 0.f;
            #pragma unroll
            for (int n = 0; n < VV; ++n) sa += A[(s*VV + n)*VV + m];
            v = fmaf(cb[s*COUT + c], sa, v);
        }
        zbias[e] = v;
    } else if (id < 27648 + 3072 + 2400 + 192) {
        stats[id - 27648 - 3072 - 2400] = 0.0f;
    }
}

// ---------------------------------------------------------------------------
// fused: per (b, t-tile of 2). Window-5 is applied AT THE x LOAD (5 guarded
// taps over t; commutes with both linear contractions), so this kernel's
// output is the final WINDOWED pre-BN tensor. 1/5 is folded into Wflat; the
// bias contribution is zbias * cnt(t)/5 where cnt = #valid taps at t.
//  phase 1: XAt[col=(tl,m)][k=(s,i)] = sum_n xw[b,i,t0+tl,n] * A[s,n,m]
//  phase 2: out[b][c][t][m] = sum_k Wflat[c][k] * XAt[col][k] + zbias*cnt/5
// ---------------------------------------------------------------------------
__global__ __launch_bounds__(256) void fused(
    const float* __restrict__ x,
    const __hip_bfloat16* __restrict__ Wflat,
    const __hip_bfloat16* __restrict__ Bfr,
    const float* __restrict__ zbias,
    float* __restrict__ out)
{
    __shared__ __hip_bfloat16 XAt[XCOLS*KK];  // 36,864 B
    const int tid  = threadIdx.x;
    const int lane = tid & 63;
    const int wave = tid >> 6;
    const int quad = lane >> 4;       // 0..3
    const int lrow = lane & 15;
    const int tile = blockIdx.x;      // 0..143
    const int b    = blockIdx.y;      // 0..31
    const int t0   = tile*2;

    // 6 B1 fragments (A_s matrices), precomputed per-lane by prep
    bf16x8 bf1[6];
    #pragma unroll
    for (int f = 0; f < 6; ++f)
        bf1[f] = *(const bf16x8*)(Bfr + (f*64 + lane)*8);

    // ---- phase 1: wave w handles M-tiles 3w..3w+2 (rows = i*2+tl)
    #pragma unroll
    for (int mt3 = 0; mt3 < 3; ++mt3) {
        const int Mtile = wave*3 + mt3;
        // A1 frag: this lane supplies row = Mtile*16 + lrow, k(=n) = quad*8+j
        const int arow = Mtile*16 + lrow;
        const int ai = arow >> 1, atl = arow & 1;
        const int t  = t0 + atl;
        const float* xr = x + ((size_t)(b*CIN + ai)*TT + t)*VV;
        float xv[8];
        #pragma unroll
        for (int j = 0; j < 8; ++j) xv[j] = 0.f;
        if (quad < 3) {
            // window-5 sum over t (guarded at edges); /5 folded into Wflat
            #pragma unroll
            for (int dt = -2; dt <= 2; ++dt) {
                if ((unsigned)(t + dt) < TT) {
                    #pragma unroll
                    for (int j = 0; j < 8; ++j) xv[j] += xr[dt*VV + quad*8 + j];
                }
            }
        } else {
            #pragma unroll
            for (int dt = -2; dt <= 2; ++dt)
                if ((unsigned)(t + dt) < TT) xv[0] += xr[dt*VV + 24];  // n=24; k=25..31 hit zero B
        }
        bf16x8 af;
        #pragma unroll
        for (int j = 0; j < 8; ++j) ((short*)&af)[j] = (short)f2bf(xv[j]);

        // D rows owned by this lane: row16 = quad*4 + r ; i0 = Mtile*8+quad*2
        const int i0 = Mtile*8 + quad*2;
        #pragma unroll
        for (int s = 0; s < SS; ++s) {
            #pragma unroll
            for (int nt = 0; nt < 2; ++nt) {
                f32x4 d = {0.f, 0.f, 0.f, 0.f};
                d = __builtin_amdgcn_mfma_f32_16x16x32_bf16(af, bf1[s*2+nt], d, 0, 0, 0);
                const int m = nt*16 + lrow;
                if (m < VV) {
                    const int k0 = s*CIN + i0;         // even
                    const int g  = k0 >> 3, o = k0 & 7;
                    #pragma unroll
                    for (int tl = 0; tl < 2; ++tl) {   // pair (d[tl], d[tl+2]) -> (i0, i0+1)
                        const int col = tl*VV + m;
                        const int gs  = (g & ~3) | ((g & 3) ^ ((col >> 1) & 3));
                        unsigned int pv = (unsigned int)f2bf(d[tl])
                                        | ((unsigned int)f2bf(d[tl+2]) << 16);
                        ((unsigned int*)XAt)[(col*KK + gs*8 + o) >> 1] = pv;
                    }
                }
            }
        }
    }
    __syncthreads();

    // ---- phase 2: wave split 2x2: mh -> c-tiles, nh -> col-tiles
    const int mh = wave & 1, nh = wave >> 1;
    f32x4 acc[3][2] = {};
    for (int it = 0; it < 9; ++it) {
        const int k0 = it*32;
        bf16x8 bfrag[2];
        #pragma unroll
        for (int ct = 0; ct < 2; ++ct) {
            const int cl = (nh*2 + ct)*16 + lrow;           // col (junk >=50 ok)
            const int g0 = it*4 + (quad ^ ((cl >> 1) & 3));
            bfrag[ct] = *(const bf16x8*)&XAt[cl*KK + g0*8];
        }
        #pragma unroll
        for (int mt = 0; mt < 3; ++mt) {
            const int c = (mh*3 + mt)*16 + lrow;
            bf16x8 afrag = *(const bf16x8*)(Wflat + c*KK + k0 + quad*8);
            #pragma unroll
            for (int ct = 0; ct < 2; ++ct)
                acc[mt][ct] = __builtin_amdgcn_mfma_f32_16x16x32_bf16(
                    afrag, bfrag[ct], acc[mt][ct], 0, 0, 0);
        }
    }

    // ---- epilogue: D col = lane&15, row = quad*4+r ; scatter + zbias*cnt/5
    #pragma unroll
    for (int ct = 0; ct < 2; ++ct) {
        const int cl = (nh*2 + ct)*16 + lrow;
        if (cl < 2*VV) {
            const int tl = (cl >= VV) ? 1 : 0;
            const int m  = cl - tl*VV;
            const int t  = t0 + tl;
            const int lo = (t-2 < 0) ? 0 : t-2;
            const int hi = (t+2 > TT-1) ? TT-1 : t+2;
            const float zs = (float)(hi - lo + 1) * 0.2f;   // cnt/5
            float* obase = out + ((size_t)b*COUT*TT + t)*VV + m;
            #pragma unroll
            for (int mt = 0; mt < 3; ++mt) {
                const int cbase = (mh*3 + mt)*16 + quad*4;
                #pragma unroll
                for (int r = 0; r < 4; ++r) {
                    const int c = cbase + r;
                    obase[(size_t)c*TV] = acc[mt][ct][r] + zbias[c*VV + m] * zs;
                }
            }
        }
    }
}

// ---------------------------------------------------------------------------
// k2: pure streaming stats on the already-windowed out. No LDS stage, no
// window logic — just float4 read + sum/sumsq + wave reduce + 2 atomics.
// ---------------------------------------------------------------------------
__global__ __launch_bounds__(256) void k2_stats(
    const float* __restrict__ zbuf, float* __restrict__ ssum, float* __restrict__ ssq)
{
    __shared__ float red[8];
    const int tid  = threadIdx.x;
    const int slab = blockIdx.x;              // b*COUT + c
    const int c    = slab % COUT;
    const float4* s4 = (const float4*)(zbuf + (size_t)slab * TV);
    float ls = 0.f, ls2 = 0.f;
    for (int e = tid; e < TV/4; e += 256) {
        float4 v = s4[e];
        ls  += (v.x + v.y) + (v.z + v.w);
        ls2 = fmaf(v.x, v.x, ls2);
        ls2 = fmaf(v.y, v.y, ls2);
        ls2 = fmaf(v.z, v.z, ls2);
        ls2 = fmaf(v.w, v.w, ls2);
    }
    #pragma unroll
    for (int off = 32; off > 0; off >>= 1) {
        ls  += __shfl_down(ls,  off, 64);
        ls2 += __shfl_down(ls2, off, 64);
    }
    const int lane = tid & 63, wid = tid >> 6;
    if (lane == 0) { red[wid*2] = ls; red[wid*2+1] = ls2; }
    __syncthreads();
    if (tid == 0) {
        atomicAdd(&ssum[c], red[0] + red[2] + red[4] + red[6]);
        atomicAdd(&ssq[c],  red[1] + red[3] + red[5] + red[7]);
    }
}

// ---------------------------------------------------------------------------
// k4: pure streaming normalize + relu, in place. k3 folded in: every block
// recomputes scale/bias from 4 scalars (deterministic, identical per c).
// ---------------------------------------------------------------------------
__global__ __launch_bounds__(256) void k4_norm(
    float* __restrict__ buf, const float* __restrict__ ssum, const float* __restrict__ ssq,
    const float* __restrict__ gamma, const float* __restrict__ beta)
{
    const int tid  = threadIdx.x;
    const int slab = blockIdx.x;              // b*COUT + c
    const int c    = slab % COUT;
    const float invN = 1.0f / (float)(BB * TV);
    const float mean = ssum[c] * invN;
    const float var  = ssq[c] * invN - mean * mean;
    const float inv  = rsqrtf(var + BN_EPS);
    const float sc   = gamma[c] * inv;
    const float bi   = beta[c] - mean * sc;
    float4* p = (float4*)(buf + (size_t)slab * TV);
    for (int u = tid; u < TV/4; u += 256) {
        float4 v = p[u];
        v.x = fmaxf(fmaf(v.x, sc, bi), 0.0f);
        v.y = fmaxf(fmaf(v.y, sc, bi), 0.0f);
        v.z = fmaxf(fmaf(v.z, sc, bi), 0.0f);
        v.w = fmaxf(fmaf(v.w, sc, bi), 0.0f);
        p[u] = v;
    }
}

extern "C" void kernel_launch(void* const* d_in, const int* in_sizes, int n_in,
                              void* d_out, int out_size, void* d_ws, size_t ws_size,
                              hipStream_t stream) {
    const float* x      = (const float*)d_in[0];
    const float* A      = (const float*)d_in[1];
    const float* conv_w = (const float*)d_in[2];
    const float* conv_b = (const float*)d_in[3];
    const float* gamma  = (const float*)d_in[4];
    const float* beta   = (const float*)d_in[5];
    float* out = (float*)d_out;

    // ws layout: zbias(2400 f) | ssum(96) | ssq(96) | Wflat (27648 bf16) | Bfr (3072 bf16)
    float* zbias = (float*)d_ws;
    float* ssum  = zbias + 2400;
    float* ssq   = ssum + COUT;
    __hip_bfloat16* Wflat = (__hip_bfloat16*)(ssq + COUT);
    __hip_bfloat16* Bfr   = Wflat + (size_t)COUT * KK;

    prep    <<<dim3(131),        dim3(256), 0, stream>>>(conv_w, A, conv_b, Wflat, Bfr, zbias, ssum);
    fused   <<<dim3(TT/2, BB),   dim3(256), 0, stream>>>(x, Wflat, Bfr, zbias, out);
    k2_stats<<<dim3(BB*COUT),    dim3(256), 0, stream>>>(out, ssum, ssq);
    k4_norm <<<dim3(BB*COUT),    dim3(256), 0, stream>>>(out, ssum, ssq, gamma, beta);
}

// Round 2
// 310.700 us; speedup vs baseline: 1.0042x; 1.0042x over previous
//
#include <hip/hip_runtime.h>
#include <hip/hip_bf16.h>

// Problem constants
#define BB 32
#define CIN 96
#define TT 288
#define VV 25
#define SS 3
#define COUT 96
#define WSZ 5
#define BN_EPS 1e-5f
#define TV (TT*VV)              // 7200
#define KK 288                  // fused GEMM K = s*96+i
#define XCOLS 64                // XAtile rows allocated (50 used; 64 so junk reads stay in-bounds)

typedef __attribute__((ext_vector_type(8))) short bf16x8;
typedef __attribute__((ext_vector_type(4))) float f32x4;

__device__ __forceinline__ unsigned short f2bf(float f) {
    unsigned u = __float_as_uint(f);
    return (unsigned short)((u + 0x7fffu + ((u >> 16) & 1u)) >> 16);  // RNE
}

// ---------------------------------------------------------------------------
// prep: Wflat[c][k=s*96+i] = bf16(0.2 * conv_w[(s*96+c)*96+i]);   // 1/WSZ folded in!
//       Bfr[f=s*2+nt][lane][j] = B-fragment of A_s for 16x16x32 MFMA
//       zbias[c*25+m] = sum_s cb[s*96+c] * sum_n A[s,n,m];  (UNscaled; ×cnt/5 at use)
//       stats[0..191] = 0.   (stats[0..95]=ssum, stats[96..191]=ssq)
// ---------------------------------------------------------------------------
__global__ __launch_bounds__(256) void prep(
    const float* __restrict__ conv_w, const float* __restrict__ A,
    const float* __restrict__ cb,
    __hip_bfloat16* __restrict__ Wflat,   // [96][288]
    __hip_bfloat16* __restrict__ Bfr,     // [6][64][8]
    float* __restrict__ zbias,            // [2400]
    float* __restrict__ stats)            // [192]
{
    int id = blockIdx.x*256 + threadIdx.x;
    if (id < 27648) {
        int c = id / KK, k = id - c*KK;
        int s = k / CIN, i = k - s*CIN;
        Wflat[id] = __float2bfloat16(0.2f * conv_w[(s*COUT + c)*CIN + i]);
    } else if (id < 27648 + 3072) {
        int e = id - 27648;               // f*512 + l*8 + j
        int f = e >> 9, rem = e & 511;
        int l = rem >> 3, j = rem & 7;
        int s = f >> 1, nt = f & 1;
        int n = (l >> 4)*8 + j;
        int m = nt*16 + (l & 15);
        float v = (n < VV && m < VV) ? A[(s*VV + n)*VV + m] : 0.0f;
        Bfr[e] = __float2bfloat16(v);
    } else if (id < 27648 + 3072 + 2400) {
        int e = id - 27648 - 3072;
        int c = e / VV, m = e - c*VV;
        float v = 0.f;
        #pragma unroll
        for (int s = 0; s < SS; ++s) {
            float sa = 0.f;
            #pragma unroll
            for (int n = 0; n < VV; ++n) sa += A[(s*VV + n)*VV + m];
            v = fmaf(cb[s*COUT + c], sa, v);
        }
        zbias[e] = v;
    } else if (id < 27648 + 3072 + 2400 + 192) {
        stats[id - 27648 - 3072 - 2400] = 0.0f;
    }
}

// ---------------------------------------------------------------------------
// fused: per (b, t-tile of 2). Window-5 applied AT THE x LOAD (5 guarded taps
// over t; commutes with both linear contractions). Output is the final
// windowed pre-BN tensor. BN sum/sumsq are reduced in the epilogue (shuffle
// over quad groups -> LDS -> global atomics), so no separate stats pass.
// XCD-chunked swizzle: tiles r*18..r*18+17 all land on XCD r (144 = 8*18,
// gridDim.x % 8 == 0 => linear%8 round-robin), making the 4-of-6 t-row
// overlap between adjacent tiles an L2 hit instead of a cross-XCD refetch.
// ---------------------------------------------------------------------------
__global__ __launch_bounds__(256) void fused(
    const float* __restrict__ x,
    const __hip_bfloat16* __restrict__ Wflat,
    const __hip_bfloat16* __restrict__ Bfr,
    const float* __restrict__ zbias,
    float* __restrict__ out,
    float* __restrict__ stats)            // [0..95]=ssum, [96..191]=ssq
{
    __shared__ __hip_bfloat16 XAt[XCOLS*KK];  // 36,864 B
    __shared__ float sh_stats[192];
    const int tid  = threadIdx.x;
    const int lane = tid & 63;
    const int wave = tid >> 6;
    const int quad = lane >> 4;       // 0..3
    const int lrow = lane & 15;
    const int px   = blockIdx.x;      // 0..143
    const int tile = ((px & 7) * 18) + (px >> 3);   // XCD-chunked, bijective
    const int b    = blockIdx.y;      // 0..31
    const int t0   = tile*2;

    if (tid < 192) sh_stats[tid] = 0.0f;   // ordered by the phase-1 barrier

    // 6 B1 fragments (A_s matrices), precomputed per-lane by prep
    bf16x8 bf1[6];
    #pragma unroll
    for (int f = 0; f < 6; ++f)
        bf1[f] = *(const bf16x8*)(Bfr + (f*64 + lane)*8);

    // ---- phase 1: wave w handles M-tiles 3w..3w+2 (rows = i*2+tl)
    #pragma unroll
    for (int mt3 = 0; mt3 < 3; ++mt3) {
        const int Mtile = wave*3 + mt3;
        // A1 frag: this lane supplies row = Mtile*16 + lrow, k(=n) = quad*8+j
        const int arow = Mtile*16 + lrow;
        const int ai = arow >> 1, atl = arow & 1;
        const int t  = t0 + atl;
        const float* xr = x + ((size_t)(b*CIN + ai)*TT + t)*VV;
        float xv[8];
        #pragma unroll
        for (int j = 0; j < 8; ++j) xv[j] = 0.f;
        if (quad < 3) {
            // window-5 sum over t (guarded at edges); /5 folded into Wflat
            #pragma unroll
            for (int dt = -2; dt <= 2; ++dt) {
                if ((unsigned)(t + dt) < TT) {
                    #pragma unroll
                    for (int j = 0; j < 8; ++j) xv[j] += xr[dt*VV + quad*8 + j];
                }
            }
        } else {
            #pragma unroll
            for (int dt = -2; dt <= 2; ++dt)
                if ((unsigned)(t + dt) < TT) xv[0] += xr[dt*VV + 24];  // n=24; k=25..31 hit zero B
        }
        bf16x8 af;
        #pragma unroll
        for (int j = 0; j < 8; ++j) ((short*)&af)[j] = (short)f2bf(xv[j]);

        // D rows owned by this lane: row16 = quad*4 + r ; i0 = Mtile*8+quad*2
        const int i0 = Mtile*8 + quad*2;
        #pragma unroll
        for (int s = 0; s < SS; ++s) {
            #pragma unroll
            for (int nt = 0; nt < 2; ++nt) {
                f32x4 d = {0.f, 0.f, 0.f, 0.f};
                d = __builtin_amdgcn_mfma_f32_16x16x32_bf16(af, bf1[s*2+nt], d, 0, 0, 0);
                const int m = nt*16 + lrow;
                if (m < VV) {
                    const int k0 = s*CIN + i0;         // even
                    const int g  = k0 >> 3, o = k0 & 7;
                    #pragma unroll
                    for (int tl = 0; tl < 2; ++tl) {   // pair (d[tl], d[tl+2]) -> (i0, i0+1)
                        const int col = tl*VV + m;
                        const int gs  = (g & ~3) | ((g & 3) ^ ((col >> 1) & 3));
                        unsigned int pv = (unsigned int)f2bf(d[tl])
                                        | ((unsigned int)f2bf(d[tl+2]) << 16);
                        ((unsigned int*)XAt)[(col*KK + gs*8 + o) >> 1] = pv;
                    }
                }
            }
        }
    }
    __syncthreads();

    // ---- phase 2: wave split 2x2: mh -> c-tiles, nh -> col-tiles
    const int mh = wave & 1, nh = wave >> 1;
    f32x4 acc[3][2] = {};
    for (int it = 0; it < 9; ++it) {
        const int k0 = it*32;
        bf16x8 bfrag[2];
        #pragma unroll
        for (int ct = 0; ct < 2; ++ct) {
            const int cl = (nh*2 + ct)*16 + lrow;           // col (junk >=50 ok)
            const int g0 = it*4 + (quad ^ ((cl >> 1) & 3));
            bfrag[ct] = *(const bf16x8*)&XAt[cl*KK + g0*8];
        }
        #pragma unroll
        for (int mt = 0; mt < 3; ++mt) {
            const int c = (mh*3 + mt)*16 + lrow;
            bf16x8 afrag = *(const bf16x8*)(Wflat + c*KK + k0 + quad*8);
            #pragma unroll
            for (int ct = 0; ct < 2; ++ct)
                acc[mt][ct] = __builtin_amdgcn_mfma_f32_16x16x32_bf16(
                    afrag, bfrag[ct], acc[mt][ct], 0, 0, 0);
        }
    }

    // ---- epilogue: D col = lane&15, row = quad*4+r ; scatter + zbias*cnt/5,
    //      and accumulate per-channel sum / sumsq for BN.
    float ps[12], pq[12];
    #pragma unroll
    for (int i = 0; i < 12; ++i) { ps[i] = 0.f; pq[i] = 0.f; }

    #pragma unroll
    for (int ct = 0; ct < 2; ++ct) {
        const int cl = (nh*2 + ct)*16 + lrow;
        if (cl < 2*VV) {
            const int tl = (cl >= VV) ? 1 : 0;
            const int m  = cl - tl*VV;
            const int t  = t0 + tl;
            const int lo = (t-2 < 0) ? 0 : t-2;
            const int hi = (t+2 > TT-1) ? TT-1 : t+2;
            const float zs = (float)(hi - lo + 1) * 0.2f;   // cnt/5
            float* obase = out + ((size_t)b*COUT*TT + t)*VV + m;
            #pragma unroll
            for (int mt = 0; mt < 3; ++mt) {
                const int cbase = (mh*3 + mt)*16 + quad*4;
                #pragma unroll
                for (int r = 0; r < 4; ++r) {
                    const int c = cbase + r;
                    const float v = acc[mt][ct][r] + zbias[c*VV + m] * zs;
                    obase[(size_t)c*TV] = v;
                    ps[mt*4 + r] += v;
                    pq[mt*4 + r] = fmaf(v, v, pq[mt*4 + r]);
                }
            }
        }
    }

    // reduce over the 16 lanes of each quad group (channel is lrow-invariant)
    #pragma unroll
    for (int off = 1; off < 16; off <<= 1) {
        #pragma unroll
        for (int i = 0; i < 12; ++i) {
            ps[i] += __shfl_xor(ps[i], off, 64);
            pq[i] += __shfl_xor(pq[i], off, 64);
        }
    }
    if (lrow == 0) {
        #pragma unroll
        for (int i = 0; i < 12; ++i) {
            const int c = (mh*3 + (i >> 2))*16 + quad*4 + (i & 3);
            atomicAdd(&sh_stats[c],      ps[i]);
            atomicAdd(&sh_stats[96 + c], pq[i]);
        }
    }
    __syncthreads();
    if (tid < 192) atomicAdd(&stats[tid], sh_stats[tid]);
}

// ---------------------------------------------------------------------------
// k4: pure streaming normalize + relu, in place. scale/bias recomputed per
// block from 4 scalars (deterministic, identical per c).
// ---------------------------------------------------------------------------
__global__ __launch_bounds__(256) void k4_norm(
    float* __restrict__ buf, const float* __restrict__ stats,
    const float* __restrict__ gamma, const float* __restrict__ beta)
{
    const int tid  = threadIdx.x;
    const int slab = blockIdx.x;              // b*COUT + c
    const int c    = slab % COUT;
    const float invN = 1.0f / (float)(BB * TV);
    const float mean = stats[c] * invN;
    const float var  = stats[96 + c] * invN - mean * mean;
    const float inv  = rsqrtf(var + BN_EPS);
    const float sc   = gamma[c] * inv;
    const float bi   = beta[c] - mean * sc;
    float4* p = (float4*)(buf + (size_t)slab * TV);
    for (int u = tid; u < TV/4; u += 256) {
        float4 v = p[u];
        v.x = fmaxf(fmaf(v.x, sc, bi), 0.0f);
        v.y = fmaxf(fmaf(v.y, sc, bi), 0.0f);
        v.z = fmaxf(fmaf(v.z, sc, bi), 0.0f);
        v.w = fmaxf(fmaf(v.w, sc, bi), 0.0f);
        p[u] = v;
    }
}

extern "C" void kernel_launch(void* const* d_in, const int* in_sizes, int n_in,
                              void* d_out, int out_size, void* d_ws, size_t ws_size,
                              hipStream_t stream) {
    const float* x      = (const float*)d_in[0];
    const float* A      = (const float*)d_in[1];
    const float* conv_w = (const float*)d_in[2];
    const float* conv_b = (const float*)d_in[3];
    const float* gamma  = (const float*)d_in[4];
    const float* beta   = (const float*)d_in[5];
    float* out = (float*)d_out;

    // ws layout: zbias(2400 f) | stats(192 f) | Wflat (27648 bf16) | Bfr (3072 bf16)
    float* zbias = (float*)d_ws;
    float* stats = zbias + 2400;
    __hip_bfloat16* Wflat = (__hip_bfloat16*)(stats + 192);
    __hip_bfloat16* Bfr   = Wflat + (size_t)COUT * KK;

    prep   <<<dim3(131),      dim3(256), 0, stream>>>(conv_w, A, conv_b, Wflat, Bfr, zbias, stats);
    fused  <<<dim3(TT/2, BB), dim3(256), 0, stream>>>(x, Wflat, Bfr, zbias, out, stats);
    k4_norm<<<dim3(BB*COUT),  dim3(256), 0, stream>>>(out, stats, gamma, beta);
}

// Round 3
// 282.925 us; speedup vs baseline: 1.1028x; 1.0982x over previous
//
#include <hip/hip_runtime.h>
#include <hip/hip_bf16.h>

// Problem constants
#define BB 32
#define CIN 96
#define TT 288
#define VV 25
#define SS 3
#define COUT 96
#define WSZ 5
#define BN_EPS 1e-5f
#define TV (TT*VV)              // 7200
#define KK 288                  // fused GEMM K = s*96+i
#define XCOLS 64                // XAtile rows allocated (50 used; 64 so junk reads stay in-bounds)
#define NBUK 64                 // stat buckets (de-contend global atomics)

typedef __attribute__((ext_vector_type(8))) short bf16x8;
typedef __attribute__((ext_vector_type(4))) float f32x4;

__device__ __forceinline__ unsigned short f2bf(float f) {
    unsigned u = __float_as_uint(f);
    return (unsigned short)((u + 0x7fffu + ((u >> 16) & 1u)) >> 16);  // RNE
}

// ---------------------------------------------------------------------------
// prep: Wflat[c][k=s*96+i] = bf16(0.2 * conv_w[(s*96+c)*96+i]);   // 1/WSZ folded in!
//       Bfr[f=s*2+nt][lane][j] = B-fragment of A_s for 16x16x32 MFMA
//       zbias[c*25+m] = sum_s cb[s*96+c] * sum_n A[s,n,m];  (UNscaled; ×cnt/5 at use)
//       stats[0 .. NBUK*192) = 0.   (per bucket: [0..95]=ssum, [96..191]=ssq)
// ---------------------------------------------------------------------------
__global__ __launch_bounds__(256) void prep(
    const float* __restrict__ conv_w, const float* __restrict__ A,
    const float* __restrict__ cb,
    __hip_bfloat16* __restrict__ Wflat,   // [96][288]
    __hip_bfloat16* __restrict__ Bfr,     // [6][64][8]
    float* __restrict__ zbias,            // [2400]
    float* __restrict__ stats)            // [NBUK*192]
{
    int id = blockIdx.x*256 + threadIdx.x;
    if (id < 27648) {
        int c = id / KK, k = id - c*KK;
        int s = k / CIN, i = k - s*CIN;
        Wflat[id] = __float2bfloat16(0.2f * conv_w[(s*COUT + c)*CIN + i]);
    } else if (id < 27648 + 3072) {
        int e = id - 27648;               // f*512 + l*8 + j
        int f = e >> 9, rem = e & 511;
        int l = rem >> 3, j = rem & 7;
        int s = f >> 1, nt = f & 1;
        int n = (l >> 4)*8 + j;
        int m = nt*16 + (l & 15);
        float v = (n < VV && m < VV) ? A[(s*VV + n)*VV + m] : 0.0f;
        Bfr[e] = __float2bfloat16(v);
    } else if (id < 27648 + 3072 + 2400) {
        int e = id - 27648 - 3072;
        int c = e / VV, m = e - c*VV;
        float v = 0.f;
        #pragma unroll
        for (int s = 0; s < SS; ++s) {
            float sa = 0.f;
            #pragma unroll
            for (int n = 0; n < VV; ++n) sa += A[(s*VV + n)*VV + m];
            v = fmaf(cb[s*COUT + c], sa, v);
        }
        zbias[e] = v;
    } else if (id < 27648 + 3072 + 2400 + NBUK*192) {
        stats[id - 27648 - 3072 - 2400] = 0.0f;
    }
}

// ---------------------------------------------------------------------------
// fused: per (b, t-tile of 2). Window-5 applied AT THE x LOAD (5 guarded taps
// over t; commutes with both linear contractions). Output is the final
// windowed pre-BN tensor. BN sum/sumsq reduced in the epilogue: 16-lane
// shuffle -> plain LDS stores (disjoint per nh slot) -> ONE bucketed global
// atomic per tid<192. Buckets kill the cross-XCD same-line serialization
// that cost ~70 us in round 2 (885k atomics on 12 lines).
// XCD-chunked swizzle: tiles r*18..r*18+17 all land on XCD r (144 = 8*18),
// making the 4-of-6 t-row overlap between adjacent tiles an L2 hit.
// ---------------------------------------------------------------------------
__global__ __launch_bounds__(256) void fused(
    const float* __restrict__ x,
    const __hip_bfloat16* __restrict__ Wflat,
    const __hip_bfloat16* __restrict__ Bfr,
    const float* __restrict__ zbias,
    float* __restrict__ out,
    float* __restrict__ stats)            // [NBUK][192]
{
    __shared__ __hip_bfloat16 XAt[XCOLS*KK];  // 36,864 B
    __shared__ float sh_stats[2][192];        // slot = nh; plain stores, fully covered
    const int tid  = threadIdx.x;
    const int lane = tid & 63;
    const int wave = tid >> 6;
    const int quad = lane >> 4;       // 0..3
    const int lrow = lane & 15;
    const int px   = blockIdx.x;      // 0..143
    const int tile = ((px & 7) * 18) + (px >> 3);   // XCD-chunked, bijective
    const int b    = blockIdx.y;      // 0..31
    const int t0   = tile*2;

    // 6 B1 fragments (A_s matrices), precomputed per-lane by prep
    bf16x8 bf1[6];
    #pragma unroll
    for (int f = 0; f < 6; ++f)
        bf1[f] = *(const bf16x8*)(Bfr + (f*64 + lane)*8);

    // ---- phase 1: wave w handles M-tiles 3w..3w+2 (rows = i*2+tl)
    #pragma unroll
    for (int mt3 = 0; mt3 < 3; ++mt3) {
        const int Mtile = wave*3 + mt3;
        // A1 frag: this lane supplies row = Mtile*16 + lrow, k(=n) = quad*8+j
        const int arow = Mtile*16 + lrow;
        const int ai = arow >> 1, atl = arow & 1;
        const int t  = t0 + atl;
        const float* xr = x + ((size_t)(b*CIN + ai)*TT + t)*VV;
        float xv[8];
        #pragma unroll
        for (int j = 0; j < 8; ++j) xv[j] = 0.f;
        if (quad < 3) {
            // window-5 sum over t (guarded at edges); /5 folded into Wflat
            #pragma unroll
            for (int dt = -2; dt <= 2; ++dt) {
                if ((unsigned)(t + dt) < TT) {
                    #pragma unroll
                    for (int j = 0; j < 8; ++j) xv[j] += xr[dt*VV + quad*8 + j];
                }
            }
        } else {
            #pragma unroll
            for (int dt = -2; dt <= 2; ++dt)
                if ((unsigned)(t + dt) < TT) xv[0] += xr[dt*VV + 24];  // n=24; k=25..31 hit zero B
        }
        bf16x8 af;
        #pragma unroll
        for (int j = 0; j < 8; ++j) ((short*)&af)[j] = (short)f2bf(xv[j]);

        // D rows owned by this lane: row16 = quad*4 + r ; i0 = Mtile*8+quad*2
        const int i0 = Mtile*8 + quad*2;
        #pragma unroll
        for (int s = 0; s < SS; ++s) {
            #pragma unroll
            for (int nt = 0; nt < 2; ++nt) {
                f32x4 d = {0.f, 0.f, 0.f, 0.f};
                d = __builtin_amdgcn_mfma_f32_16x16x32_bf16(af, bf1[s*2+nt], d, 0, 0, 0);
                const int m = nt*16 + lrow;
                if (m < VV) {
                    const int k0 = s*CIN + i0;         // even
                    const int g  = k0 >> 3, o = k0 & 7;
                    #pragma unroll
                    for (int tl = 0; tl < 2; ++tl) {   // pair (d[tl], d[tl+2]) -> (i0, i0+1)
                        const int col = tl*VV + m;
                        const int gs  = (g & ~3) | ((g & 3) ^ ((col >> 1) & 3));
                        unsigned int pv = (unsigned int)f2bf(d[tl])
                                        | ((unsigned int)f2bf(d[tl+2]) << 16);
                        ((unsigned int*)XAt)[(col*KK + gs*8 + o) >> 1] = pv;
                    }
                }
            }
        }
    }
    __syncthreads();

    // ---- phase 2: wave split 2x2: mh -> c-tiles, nh -> col-tiles
    const int mh = wave & 1, nh = wave >> 1;
    f32x4 acc[3][2] = {};
    for (int it = 0; it < 9; ++it) {
        const int k0 = it*32;
        bf16x8 bfrag[2];
        #pragma unroll
        for (int ct = 0; ct < 2; ++ct) {
            const int cl = (nh*2 + ct)*16 + lrow;           // col (junk >=50 ok)
            const int g0 = it*4 + (quad ^ ((cl >> 1) & 3));
            bfrag[ct] = *(const bf16x8*)&XAt[cl*KK + g0*8];
        }
        #pragma unroll
        for (int mt = 0; mt < 3; ++mt) {
            const int c = (mh*3 + mt)*16 + lrow;
            bf16x8 afrag = *(const bf16x8*)(Wflat + c*KK + k0 + quad*8);
            #pragma unroll
            for (int ct = 0; ct < 2; ++ct)
                acc[mt][ct] = __builtin_amdgcn_mfma_f32_16x16x32_bf16(
                    afrag, bfrag[ct], acc[mt][ct], 0, 0, 0);
        }
    }

    // ---- epilogue: D col = lane&15, row = quad*4+r ; scatter + zbias*cnt/5,
    //      and accumulate per-channel sum / sumsq for BN.
    float ps[12], pq[12];
    #pragma unroll
    for (int i = 0; i < 12; ++i) { ps[i] = 0.f; pq[i] = 0.f; }

    #pragma unroll
    for (int ct = 0; ct < 2; ++ct) {
        const int cl = (nh*2 + ct)*16 + lrow;
        if (cl < 2*VV) {
            const int tl = (cl >= VV) ? 1 : 0;
            const int m  = cl - tl*VV;
            const int t  = t0 + tl;
            const int lo = (t-2 < 0) ? 0 : t-2;
            const int hi = (t+2 > TT-1) ? TT-1 : t+2;
            const float zs = (float)(hi - lo + 1) * 0.2f;   // cnt/5
            float* obase = out + ((size_t)b*COUT*TT + t)*VV + m;
            #pragma unroll
            for (int mt = 0; mt < 3; ++mt) {
                const int cbase = (mh*3 + mt)*16 + quad*4;
                #pragma unroll
                for (int r = 0; r < 4; ++r) {
                    const int c = cbase + r;
                    const float v = acc[mt][ct][r] + zbias[c*VV + m] * zs;
                    obase[(size_t)c*TV] = v;
                    ps[mt*4 + r] += v;
                    pq[mt*4 + r] = fmaf(v, v, pq[mt*4 + r]);
                }
            }
        }
    }

    // reduce over the 16 lanes of each quad group (channel is lrow-invariant)
    #pragma unroll
    for (int off = 1; off < 16; off <<= 1) {
        #pragma unroll
        for (int i = 0; i < 12; ++i) {
            ps[i] += __shfl_xor(ps[i], off, 64);
            pq[i] += __shfl_xor(pq[i], off, 64);
        }
    }
    // plain LDS stores: slot nh; waves mh=0/1 cover channels 0..47 / 48..95
    if (lrow == 0) {
        #pragma unroll
        for (int i = 0; i < 12; ++i) {
            const int c = (mh*3 + (i >> 2))*16 + quad*4 + (i & 3);
            sh_stats[nh][c]      = ps[i];
            sh_stats[nh][96 + c] = pq[i];
        }
    }
    __syncthreads();
    if (tid < 192) {
        const int bucket = (px + b) & (NBUK - 1);
        atomicAdd(&stats[bucket*192 + tid], sh_stats[0][tid] + sh_stats[1][tid]);
    }
}

// ---------------------------------------------------------------------------
// k4: reduce the NBUK stat buckets for this channel (uniform scalar loads,
// L2-hit), then pure streaming normalize + relu, in place.
// ---------------------------------------------------------------------------
__global__ __launch_bounds__(256) void k4_norm(
    float* __restrict__ buf, const float* __restrict__ stats,
    const float* __restrict__ gamma, const float* __restrict__ beta)
{
    const int tid  = threadIdx.x;
    const int slab = blockIdx.x;              // b*COUT + c
    const int c    = slab % COUT;
    float s0 = 0.f, s1 = 0.f;
    #pragma unroll 8
    for (int u = 0; u < NBUK; ++u) {
        s0 += stats[u*192 + c];
        s1 += stats[u*192 + 96 + c];
    }
    const float invN = 1.0f / (float)(BB * TV);
    const float mean = s0 * invN;
    const float var  = s1 * invN - mean * mean;
    const float inv  = rsqrtf(var + BN_EPS);
    const float sc   = gamma[c] * inv;
    const float bi   = beta[c] - mean * sc;
    float4* p = (float4*)(buf + (size_t)slab * TV);
    for (int u = tid; u < TV/4; u += 256) {
        float4 v = p[u];
        v.x = fmaxf(fmaf(v.x, sc, bi), 0.0f);
        v.y = fmaxf(fmaf(v.y, sc, bi), 0.0f);
        v.z = fmaxf(fmaf(v.z, sc, bi), 0.0f);
        v.w = fmaxf(fmaf(v.w, sc, bi), 0.0f);
        p[u] = v;
    }
}

extern "C" void kernel_launch(void* const* d_in, const int* in_sizes, int n_in,
                              void* d_out, int out_size, void* d_ws, size_t ws_size,
                              hipStream_t stream) {
    const float* x      = (const float*)d_in[0];
    const float* A      = (const float*)d_in[1];
    const float* conv_w = (const float*)d_in[2];
    const float* conv_b = (const float*)d_in[3];
    const float* gamma  = (const float*)d_in[4];
    const float* beta   = (const float*)d_in[5];
    float* out = (float*)d_out;

    // ws layout: zbias(2400 f) | stats(NBUK*192 f) | Wflat (27648 bf16) | Bfr (3072 bf16)
    float* zbias = (float*)d_ws;
    float* stats = zbias + 2400;
    __hip_bfloat16* Wflat = (__hip_bfloat16*)(stats + NBUK*192);
    __hip_bfloat16* Bfr   = Wflat + (size_t)COUT * KK;

    // prep thread count: 27648 + 3072 + 2400 + NBUK*192 = 45,408 -> 178 blocks
    prep   <<<dim3(178),      dim3(256), 0, stream>>>(conv_w, A, conv_b, Wflat, Bfr, zbias, stats);
    fused  <<<dim3(TT/2, BB), dim3(256), 0, stream>>>(x, Wflat, Bfr, zbias, out, stats);
    k4_norm<<<dim3(BB*COUT),  dim3(256), 0, stream>>>(out, stats, gamma, beta);
}

// Round 4
// 264.182 us; speedup vs baseline: 1.1810x; 1.0709x over previous
//
#include <hip/hip_runtime.h>
#include <hip/hip_bf16.h>

// Problem constants
#define BB 32
#define CIN 96
#define TT 288
#define VV 25
#define SS 3
#define COUT 96
#define WSZ 5
#define BN_EPS 1e-5f
#define TV (TT*VV)              // 7200
#define KK 288                  // fused GEMM K = s*96+i
#define XCOLS 50                // XAtile rows: exactly 2*VV used; junk reads clamped
#define NBUK 64                 // stat buckets (de-contend global atomics)

typedef __attribute__((ext_vector_type(8))) short bf16x8;
typedef __attribute__((ext_vector_type(4))) float f32x4;

__device__ __forceinline__ unsigned short f2bf(float f) {
    unsigned u = __float_as_uint(f);
    return (unsigned short)((u + 0x7fffu + ((u >> 16) & 1u)) >> 16);  // RNE
}

// ---------------------------------------------------------------------------
// prep: Wflat[c][k=s*96+i] = bf16(0.2 * conv_w[(s*96+c)*96+i]);   // 1/WSZ folded in!
//       Bfr[f=s*2+nt][lane][j] = B-fragment of A_s for 16x16x32 MFMA
//       zbias[c*25+m] = sum_s cb[s*96+c] * sum_n A[s,n,m];  (UNscaled; ×cnt/5 at use)
//       stats[0 .. NBUK*192) = 0.   (per bucket: [0..95]=ssum, [96..191]=ssq)
// ---------------------------------------------------------------------------
__global__ __launch_bounds__(256) void prep(
    const float* __restrict__ conv_w, const float* __restrict__ A,
    const float* __restrict__ cb,
    __hip_bfloat16* __restrict__ Wflat,   // [96][288]
    __hip_bfloat16* __restrict__ Bfr,     // [6][64][8]
    float* __restrict__ zbias,            // [2400]
    float* __restrict__ stats)            // [NBUK*192]
{
    int id = blockIdx.x*256 + threadIdx.x;
    if (id < 27648) {
        int c = id / KK, k = id - c*KK;
        int s = k / CIN, i = k - s*CIN;
        Wflat[id] = __float2bfloat16(0.2f * conv_w[(s*COUT + c)*CIN + i]);
    } else if (id < 27648 + 3072) {
        int e = id - 27648;               // f*512 + l*8 + j
        int f = e >> 9, rem = e & 511;
        int l = rem >> 3, j = rem & 7;
        int s = f >> 1, nt = f & 1;
        int n = (l >> 4)*8 + j;
        int m = nt*16 + (l & 15);
        float v = (n < VV && m < VV) ? A[(s*VV + n)*VV + m] : 0.0f;
        Bfr[e] = __float2bfloat16(v);
    } else if (id < 27648 + 3072 + 2400) {
        int e = id - 27648 - 3072;
        int c = e / VV, m = e - c*VV;
        float v = 0.f;
        #pragma unroll
        for (int s = 0; s < SS; ++s) {
            float sa = 0.f;
            #pragma unroll
            for (int n = 0; n < VV; ++n) sa += A[(s*VV + n)*VV + m];
            v = fmaf(cb[s*COUT + c], sa, v);
        }
        zbias[e] = v;
    } else if (id < 27648 + 3072 + 2400 + NBUK*192) {
        stats[id - 27648 - 3072 - 2400] = 0.0f;
    }
}

// ---------------------------------------------------------------------------
// fused: per (b, t-tile of 2). Window-5 applied AT THE x LOAD; even/odd lane
// pairing: each lane loads only taps {t-2, t, t+2} (3 vec loads, block-
// uniform edge guards) and swaps the 2-tap partial its partner needs via
// __shfl_xor(.,1): atl=0 sends l1+l2 / receives partner l0+l1, and v.v.
// Output is the final windowed pre-BN tensor. BN sum/sumsq reduced in the
// epilogue: 16-lane shuffle -> plain LDS stores -> ONE bucketed global
// atomic per tid<192 (NBUK buckets kill cross-XCD same-line serialization).
// XCD-chunked swizzle: tiles r*18..r*18+17 all land on XCD r (144 = 8*18),
// making the 4-of-6 t-row overlap between adjacent tiles an L2 hit.
// XCOLS=50 (28.8 KB XAt) -> 5 blocks/CU for latency hiding; junk col reads
// in phase 2 are clamped to col 49 (broadcast; data discarded by cl<50).
// ---------------------------------------------------------------------------
__global__ __launch_bounds__(256) void fused(
    const float* __restrict__ x,
    const __hip_bfloat16* __restrict__ Wflat,
    const __hip_bfloat16* __restrict__ Bfr,
    const float* __restrict__ zbias,
    float* __restrict__ out,
    float* __restrict__ stats)            // [NBUK][192]
{
    __shared__ __hip_bfloat16 XAt[XCOLS*KK];  // 28,800 B
    __shared__ float sh_stats[2][192];        // slot = nh; plain stores, fully covered
    const int tid  = threadIdx.x;
    const int lane = tid & 63;
    const int wave = tid >> 6;
    const int quad = lane >> 4;       // 0..3
    const int lrow = lane & 15;
    const int px   = blockIdx.x;      // 0..143
    const int tile = ((px & 7) * 18) + (px >> 3);   // XCD-chunked, bijective
    const int b    = blockIdx.y;      // 0..31
    const int t0   = tile*2;

    // 6 B1 fragments (A_s matrices), precomputed per-lane by prep
    bf16x8 bf1[6];
    #pragma unroll
    for (int f = 0; f < 6; ++f)
        bf1[f] = *(const bf16x8*)(Bfr + (f*64 + lane)*8);

    // ---- phase 1: wave w handles M-tiles 3w..3w+2 (rows = i*2+tl)
    #pragma unroll
    for (int mt3 = 0; mt3 < 3; ++mt3) {
        const int Mtile = wave*3 + mt3;
        // A1 frag: this lane supplies row = Mtile*16 + lrow, k(=n) = quad*8+j
        const int arow = Mtile*16 + lrow;
        const int ai = arow >> 1, atl = arow & 1;
        const int t  = t0 + atl;
        const float* xr = x + ((size_t)(b*CIN + ai)*TT + t)*VV;
        float l0[8], l1[8], l2[8];
        if (quad < 3) {
            const int off = quad*8;
            #pragma unroll
            for (int j = 0; j < 8; ++j) l1[j] = xr[off + j];
            if (tile != 0) {
                #pragma unroll
                for (int j = 0; j < 8; ++j) l0[j] = xr[-2*VV + off + j];
            } else {
                #pragma unroll
                for (int j = 0; j < 8; ++j) l0[j] = 0.f;
            }
            if (tile != TT/2 - 1) {
                #pragma unroll
                for (int j = 0; j < 8; ++j) l2[j] = xr[2*VV + off + j];
            } else {
                #pragma unroll
                for (int j = 0; j < 8; ++j) l2[j] = 0.f;
            }
        } else {
            #pragma unroll
            for (int j = 0; j < 8; ++j) { l0[j] = 0.f; l1[j] = 0.f; l2[j] = 0.f; }
            l1[0] = xr[24];                                  // n=24; k=25..31 hit zero B
            if (tile != 0)        l0[0] = xr[-2*VV + 24];
            if (tile != TT/2 - 1) l2[0] = xr[ 2*VV + 24];
        }
        // window-5 via pair exchange: xw = (l0+l1+l2) + partner 2-tap partial
        float xv[8];
        #pragma unroll
        for (int j = 0; j < 8; ++j) {
            const float s    = l0[j] + l1[j] + l2[j];
            const float give = atl ? (l0[j] + l1[j]) : (l1[j] + l2[j]);
            const float recv = __shfl_xor(give, 1, 64);
            xv[j] = s + recv;
        }
        bf16x8 af;
        #pragma unroll
        for (int j = 0; j < 8; ++j) ((short*)&af)[j] = (short)f2bf(xv[j]);

        // D rows owned by this lane: row16 = quad*4 + r ; i0 = Mtile*8+quad*2
        const int i0 = Mtile*8 + quad*2;
        #pragma unroll
        for (int s = 0; s < SS; ++s) {
            #pragma unroll
            for (int nt = 0; nt < 2; ++nt) {
                f32x4 d = {0.f, 0.f, 0.f, 0.f};
                d = __builtin_amdgcn_mfma_f32_16x16x32_bf16(af, bf1[s*2+nt], d, 0, 0, 0);
                const int m = nt*16 + lrow;
                if (m < VV) {
                    const int k0 = s*CIN + i0;         // even
                    const int g  = k0 >> 3, o = k0 & 7;
                    #pragma unroll
                    for (int tl = 0; tl < 2; ++tl) {   // pair (d[tl], d[tl+2]) -> (i0, i0+1)
                        const int col = tl*VV + m;
                        const int gs  = (g & ~3) | ((g & 3) ^ ((col >> 1) & 3));
                        unsigned int pv = (unsigned int)f2bf(d[tl])
                                        | ((unsigned int)f2bf(d[tl+2]) << 16);
                        ((unsigned int*)XAt)[(col*KK + gs*8 + o) >> 1] = pv;
                    }
                }
            }
        }
    }
    __syncthreads();

    // ---- phase 2: wave split 2x2: mh -> c-tiles, nh -> col-tiles
    const int mh = wave & 1, nh = wave >> 1;
    f32x4 acc[3][2] = {};
    for (int it = 0; it < 9; ++it) {
        const int k0 = it*32;
        bf16x8 bfrag[2];
        #pragma unroll
        for (int ct = 0; ct < 2; ++ct) {
            const int cl  = (nh*2 + ct)*16 + lrow;
            const int clr = (cl < 2*VV) ? cl : (2*VV - 1);  // clamp junk cols (broadcast)
            const int g0  = it*4 + (quad ^ ((clr >> 1) & 3));
            bfrag[ct] = *(const bf16x8*)&XAt[clr*KK + g0*8];
        }
        #pragma unroll
        for (int mt = 0; mt < 3; ++mt) {
            const int c = (mh*3 + mt)*16 + lrow;
            bf16x8 afrag = *(const bf16x8*)(Wflat + c*KK + k0 + quad*8);
            #pragma unroll
            for (int ct = 0; ct < 2; ++ct)
                acc[mt][ct] = __builtin_amdgcn_mfma_f32_16x16x32_bf16(
                    afrag, bfrag[ct], acc[mt][ct], 0, 0, 0);
        }
    }

    // ---- epilogue: D col = lane&15, row = quad*4+r ; scatter + zbias*cnt/5,
    //      and accumulate per-channel sum / sumsq for BN.
    float ps[12], pq[12];
    #pragma unroll
    for (int i = 0; i < 12; ++i) { ps[i] = 0.f; pq[i] = 0.f; }

    #pragma unroll
    for (int ct = 0; ct < 2; ++ct) {
        const int cl = (nh*2 + ct)*16 + lrow;
        if (cl < 2*VV) {
            const int tl = (cl >= VV) ? 1 : 0;
            const int m  = cl - tl*VV;
            const int t  = t0 + tl;
            const int lo = (t-2 < 0) ? 0 : t-2;
            const int hi = (t+2 > TT-1) ? TT-1 : t+2;
            const float zs = (float)(hi - lo + 1) * 0.2f;   // cnt/5
            float* obase = out + ((size_t)b*COUT*TT + t)*VV + m;
            #pragma unroll
            for (int mt = 0; mt < 3; ++mt) {
                const int cbase = (mh*3 + mt)*16 + quad*4;
                #pragma unroll
                for (int r = 0; r < 4; ++r) {
                    const int c = cbase + r;
                    const float v = acc[mt][ct][r] + zbias[c*VV + m] * zs;
                    obase[(size_t)c*TV] = v;
                    ps[mt*4 + r] += v;
                    pq[mt*4 + r] = fmaf(v, v, pq[mt*4 + r]);
                }
            }
        }
    }

    // reduce over the 16 lanes of each quad group (channel is lrow-invariant)
    #pragma unroll
    for (int off = 1; off < 16; off <<= 1) {
        #pragma unroll
        for (int i = 0; i < 12; ++i) {
            ps[i] += __shfl_xor(ps[i], off, 64);
            pq[i] += __shfl_xor(pq[i], off, 64);
        }
    }
    // plain LDS stores: slot nh; waves mh=0/1 cover channels 0..47 / 48..95
    if (lrow == 0) {
        #pragma unroll
        for (int i = 0; i < 12; ++i) {
            const int c = (mh*3 + (i >> 2))*16 + quad*4 + (i & 3);
            sh_stats[nh][c]      = ps[i];
            sh_stats[nh][96 + c] = pq[i];
        }
    }
    __syncthreads();
    if (tid < 192) {
        const int bucket = (px + b) & (NBUK - 1);
        atomicAdd(&stats[bucket*192 + tid], sh_stats[0][tid] + sh_stats[1][tid]);
    }
}

// ---------------------------------------------------------------------------
// k4: reduce the NBUK stat buckets for this channel (uniform scalar loads,
// L2-hit), then pure streaming normalize + relu, in place.
// ---------------------------------------------------------------------------
__global__ __launch_bounds__(256) void k4_norm(
    float* __restrict__ buf, const float* __restrict__ stats,
    const float* __restrict__ gamma, const float* __restrict__ beta)
{
    const int tid  = threadIdx.x;
    const int slab = blockIdx.x;              // b*COUT + c
    const int c    = slab % COUT;
    float s0 = 0.f, s1 = 0.f;
    #pragma unroll 8
    for (int u = 0; u < NBUK; ++u) {
        s0 += stats[u*192 + c];
        s1 += stats[u*192 + 96 + c];
    }
    const float invN = 1.0f / (float)(BB * TV);
    const float mean = s0 * invN;
    const float var  = s1 * invN - mean * mean;
    const float inv  = rsqrtf(var + BN_EPS);
    const float sc   = gamma[c] * inv;
    const float bi   = beta[c] - mean * sc;
    float4* p = (float4*)(buf + (size_t)slab * TV);
    for (int u = tid; u < TV/4; u += 256) {
        float4 v = p[u];
        v.x = fmaxf(fmaf(v.x, sc, bi), 0.0f);
        v.y = fmaxf(fmaf(v.y, sc, bi), 0.0f);
        v.z = fmaxf(fmaf(v.z, sc, bi), 0.0f);
        v.w = fmaxf(fmaf(v.w, sc, bi), 0.0f);
        p[u] = v;
    }
}

extern "C" void kernel_launch(void* const* d_in, const int* in_sizes, int n_in,
                              void* d_out, int out_size, void* d_ws, size_t ws_size,
                              hipStream_t stream) {
    const float* x      = (const float*)d_in[0];
    const float* A      = (const float*)d_in[1];
    const float* conv_w = (const float*)d_in[2];
    const float* conv_b = (const float*)d_in[3];
    const float* gamma  = (const float*)d_in[4];
    const float* beta   = (const float*)d_in[5];
    float* out = (float*)d_out;

    // ws layout: zbias(2400 f) | stats(NBUK*192 f) | Wflat (27648 bf16) | Bfr (3072 bf16)
    float* zbias = (float*)d_ws;
    float* stats = zbias + 2400;
    __hip_bfloat16* Wflat = (__hip_bfloat16*)(stats + NBUK*192);
    __hip_bfloat16* Bfr   = Wflat + (size_t)COUT * KK;

    // prep thread count: 27648 + 3072 + 2400 + NBUK*192 = 45,408 -> 178 blocks
    prep   <<<dim3(178),      dim3(256), 0, stream>>>(conv_w, A, conv_b, Wflat, Bfr, zbias, stats);
    fused  <<<dim3(TT/2, BB), dim3(256), 0, stream>>>(x, Wflat, Bfr, zbias, out, stats);
    k4_norm<<<dim3(BB*COUT),  dim3(256), 0, stream>>>(out, stats, gamma, beta);
}

// Round 5
// 263.337 us; speedup vs baseline: 1.1848x; 1.0032x over previous
//
#include <hip/hip_runtime.h>
#include <hip/hip_bf16.h>

// Problem constants
#define BB 32
#define CIN 96
#define TT 288
#define VV 25
#define SS 3
#define COUT 96
#define WSZ 5
#define BN_EPS 1e-5f
#define TV (TT*VV)              // 7200
#define KK 288                  // fused GEMM K = s*96+i
#define XCOLS 50                // XAtile rows: exactly 2*VV used; junk reads clamped
#define NBUK 64                 // stat buckets (de-contend global atomics)

typedef __attribute__((ext_vector_type(8))) short bf16x8;
typedef __attribute__((ext_vector_type(4))) float f32x4;

__device__ __forceinline__ unsigned short f2bf(float f) {
    unsigned u = __float_as_uint(f);
    return (unsigned short)((u + 0x7fffu + ((u >> 16) & 1u)) >> 16);  // RNE
}

// HW packed f32->bf16 (RNE), one instruction for a pair: lo -> bits[15:0]
__device__ __forceinline__ unsigned cvt_pk_bf16(float lo, float hi) {
    unsigned r;
    asm("v_cvt_pk_bf16_f32 %0, %1, %2" : "=v"(r) : "v"(lo), "v"(hi));
    return r;
}

// ---------------------------------------------------------------------------
// prep: Wflat[c][k=s*96+i] = bf16(0.2 * conv_w[(s*96+c)*96+i]);   // 1/WSZ folded in!
//       Bfr[f=s*2+nt][lane][j] = B-fragment of A_s for 16x16x32 MFMA
//       zbias[c*25+m] = sum_s cb[s*96+c] * sum_n A[s,n,m];  (UNscaled; ×cnt/5 at use)
//       stats[0 .. NBUK*192) = 0.   (per bucket: [0..95]=ssum, [96..191]=ssq)
// ---------------------------------------------------------------------------
__global__ __launch_bounds__(256) void prep(
    const float* __restrict__ conv_w, const float* __restrict__ A,
    const float* __restrict__ cb,
    __hip_bfloat16* __restrict__ Wflat,   // [96][288]
    __hip_bfloat16* __restrict__ Bfr,     // [6][64][8]
    float* __restrict__ zbias,            // [2400]
    float* __restrict__ stats)            // [NBUK*192]
{
    int id = blockIdx.x*256 + threadIdx.x;
    if (id < 27648) {
        int c = id / KK, k = id - c*KK;
        int s = k / CIN, i = k - s*CIN;
        Wflat[id] = __float2bfloat16(0.2f * conv_w[(s*COUT + c)*CIN + i]);
    } else if (id < 27648 + 3072) {
        int e = id - 27648;               // f*512 + l*8 + j
        int f = e >> 9, rem = e & 511;
        int l = rem >> 3, j = rem & 7;
        int s = f >> 1, nt = f & 1;
        int n = (l >> 4)*8 + j;
        int m = nt*16 + (l & 15);
        float v = (n < VV && m < VV) ? A[(s*VV + n)*VV + m] : 0.0f;
        Bfr[e] = __float2bfloat16(v);
    } else if (id < 27648 + 3072 + 2400) {
        int e = id - 27648 - 3072;
        int c = e / VV, m = e - c*VV;
        float v = 0.f;
        #pragma unroll
        for (int s = 0; s < SS; ++s) {
            float sa = 0.f;
            #pragma unroll
            for (int n = 0; n < VV; ++n) sa += A[(s*VV + n)*VV + m];
            v = fmaf(cb[s*COUT + c], sa, v);
        }
        zbias[e] = v;
    } else if (id < 27648 + 3072 + 2400 + NBUK*192) {
        stats[id - 27648 - 3072 - 2400] = 0.0f;
    }
}

// ---------------------------------------------------------------------------
// fused: per (b, t-tile of 2). Window-5 applied AT THE x LOAD; even/odd lane
// pairing: each lane loads only taps {t-2, t, t+2} (block-uniform edge
// guards) and swaps the 2-tap partial its partner needs via __shfl_xor(.,1).
// All f32->bf16 conversions use v_cvt_pk_bf16_f32 (1 instr per pair; was 5
// VALU ops per element -> ~1000 cy/wave saved). Phase 2 register-double-
// buffers afrag (L2) and bfrag (LDS) across the 9-iter K-loop so load
// latency hides under the MFMA cluster.
// BN sum/sumsq reduced in the epilogue -> bucketed global atomics (NBUK).
// XCD-chunked swizzle: tiles r*18..r*18+17 all land on XCD r (144 = 8*18).
// ---------------------------------------------------------------------------
__global__ __launch_bounds__(256) void fused(
    const float* __restrict__ x,
    const __hip_bfloat16* __restrict__ Wflat,
    const __hip_bfloat16* __restrict__ Bfr,
    const float* __restrict__ zbias,
    float* __restrict__ out,
    float* __restrict__ stats)            // [NBUK][192]
{
    __shared__ __hip_bfloat16 XAt[XCOLS*KK];  // 28,800 B
    __shared__ float sh_stats[2][192];        // slot = nh; plain stores, fully covered
    const int tid  = threadIdx.x;
    const int lane = tid & 63;
    const int wave = tid >> 6;
    const int quad = lane >> 4;       // 0..3
    const int lrow = lane & 15;
    const int px   = blockIdx.x;      // 0..143
    const int tile = ((px & 7) * 18) + (px >> 3);   // XCD-chunked, bijective
    const int b    = blockIdx.y;      // 0..31
    const int t0   = tile*2;

    // 6 B1 fragments (A_s matrices), precomputed per-lane by prep
    bf16x8 bf1[6];
    #pragma unroll
    for (int f = 0; f < 6; ++f)
        bf1[f] = *(const bf16x8*)(Bfr + (f*64 + lane)*8);

    // ---- phase 1: wave w handles M-tiles 3w..3w+2 (rows = i*2+tl)
    #pragma unroll
    for (int mt3 = 0; mt3 < 3; ++mt3) {
        const int Mtile = wave*3 + mt3;
        // A1 frag: this lane supplies row = Mtile*16 + lrow, k(=n) = quad*8+j
        const int arow = Mtile*16 + lrow;
        const int ai = arow >> 1, atl = arow & 1;
        const int t  = t0 + atl;
        const float* xr = x + ((size_t)(b*CIN + ai)*TT + t)*VV;
        float l0[8], l1[8], l2[8];
        if (quad < 3) {
            const int off = quad*8;
            #pragma unroll
            for (int j = 0; j < 8; ++j) l1[j] = xr[off + j];
            if (tile != 0) {
                #pragma unroll
                for (int j = 0; j < 8; ++j) l0[j] = xr[-2*VV + off + j];
            } else {
                #pragma unroll
                for (int j = 0; j < 8; ++j) l0[j] = 0.f;
            }
            if (tile != TT/2 - 1) {
                #pragma unroll
                for (int j = 0; j < 8; ++j) l2[j] = xr[2*VV + off + j];
            } else {
                #pragma unroll
                for (int j = 0; j < 8; ++j) l2[j] = 0.f;
            }
        } else {
            #pragma unroll
            for (int j = 0; j < 8; ++j) { l0[j] = 0.f; l1[j] = 0.f; l2[j] = 0.f; }
            l1[0] = xr[24];                                  // n=24; k=25..31 hit zero B
            if (tile != 0)        l0[0] = xr[-2*VV + 24];
            if (tile != TT/2 - 1) l2[0] = xr[ 2*VV + 24];
        }
        // window-5 via pair exchange: xw = (l0+l1+l2) + partner 2-tap partial
        float xv[8];
        #pragma unroll
        for (int j = 0; j < 8; ++j) {
            const float s    = l0[j] + l1[j] + l2[j];
            const float give = atl ? (l0[j] + l1[j]) : (l1[j] + l2[j]);
            const float recv = __shfl_xor(give, 1, 64);
            xv[j] = s + recv;
        }
        bf16x8 af;
        #pragma unroll
        for (int j2 = 0; j2 < 4; ++j2)
            ((unsigned*)&af)[j2] = cvt_pk_bf16(xv[2*j2], xv[2*j2 + 1]);

        // D rows owned by this lane: row16 = quad*4 + r ; i0 = Mtile*8+quad*2
        const int i0 = Mtile*8 + quad*2;
        #pragma unroll
        for (int s = 0; s < SS; ++s) {
            #pragma unroll
            for (int nt = 0; nt < 2; ++nt) {
                f32x4 d = {0.f, 0.f, 0.f, 0.f};
                d = __builtin_amdgcn_mfma_f32_16x16x32_bf16(af, bf1[s*2+nt], d, 0, 0, 0);
                const int m = nt*16 + lrow;
                if (m < VV) {
                    const int k0 = s*CIN + i0;         // even
                    const int g  = k0 >> 3, o = k0 & 7;
                    #pragma unroll
                    for (int tl = 0; tl < 2; ++tl) {   // pair (d[tl], d[tl+2]) -> (i0, i0+1)
                        const int col = tl*VV + m;
                        const int gs  = (g & ~3) | ((g & 3) ^ ((col >> 1) & 3));
                        const unsigned pv = cvt_pk_bf16(d[tl], d[tl+2]);
                        ((unsigned int*)XAt)[(col*KK + gs*8 + o) >> 1] = pv;
                    }
                }
            }
        }
    }
    __syncthreads();

    // ---- phase 2: wave split 2x2: mh -> c-tiles, nh -> col-tiles.
    // Register double-buffer: preload it+1's afrag (L2) + bfrag (LDS) before
    // consuming it's fragments in the MFMA cluster.
    const int mh = wave & 1, nh = wave >> 1;
    const int clr0 = ((nh*2 + 0)*16 + lrow < 2*VV) ? (nh*2+0)*16+lrow : 2*VV-1;
    const int clr1 = ((nh*2 + 1)*16 + lrow < 2*VV) ? (nh*2+1)*16+lrow : 2*VV-1;
    const int bx0  = quad ^ ((clr0 >> 1) & 3);
    const int bx1  = quad ^ ((clr1 >> 1) & 3);
    const __hip_bfloat16* wbase = Wflat + ((mh*3)*16 + lrow)*KK + quad*8;

    f32x4 acc[3][2] = {};
    bf16x8 aN[3], bN[2];
    #pragma unroll
    for (int mt = 0; mt < 3; ++mt) aN[mt] = *(const bf16x8*)(wbase + mt*16*KK);
    bN[0] = *(const bf16x8*)&XAt[clr0*KK + bx0*8];
    bN[1] = *(const bf16x8*)&XAt[clr1*KK + bx1*8];

    for (int it = 0; it < 9; ++it) {
        bf16x8 aC[3] = {aN[0], aN[1], aN[2]};
        bf16x8 bC[2] = {bN[0], bN[1]};
        if (it < 8) {
            const int k1 = (it+1)*32;
            #pragma unroll
            for (int mt = 0; mt < 3; ++mt) aN[mt] = *(const bf16x8*)(wbase + mt*16*KK + k1);
            bN[0] = *(const bf16x8*)&XAt[clr0*KK + ((it+1)*4 + bx0)*8];
            bN[1] = *(const bf16x8*)&XAt[clr1*KK + ((it+1)*4 + bx1)*8];
        }
        #pragma unroll
        for (int mt = 0; mt < 3; ++mt) {
            #pragma unroll
            for (int ct = 0; ct < 2; ++ct)
                acc[mt][ct] = __builtin_amdgcn_mfma_f32_16x16x32_bf16(
                    aC[mt], bC[ct], acc[mt][ct], 0, 0, 0);
        }
    }

    // ---- epilogue: D col = lane&15, row = quad*4+r ; scatter + zbias*cnt/5,
    //      and accumulate per-channel sum / sumsq for BN.
    float ps[12], pq[12];
    #pragma unroll
    for (int i = 0; i < 12; ++i) { ps[i] = 0.f; pq[i] = 0.f; }

    #pragma unroll
    for (int ct = 0; ct < 2; ++ct) {
        const int cl = (nh*2 + ct)*16 + lrow;
        if (cl < 2*VV) {
            const int tl = (cl >= VV) ? 1 : 0;
            const int m  = cl - tl*VV;
            const int t  = t0 + tl;
            const int lo = (t-2 < 0) ? 0 : t-2;
            const int hi = (t+2 > TT-1) ? TT-1 : t+2;
            const float zs = (float)(hi - lo + 1) * 0.2f;   // cnt/5
            float* obase = out + ((size_t)b*COUT*TT + t)*VV + m;
            #pragma unroll
            for (int mt = 0; mt < 3; ++mt) {
                const int cbase = (mh*3 + mt)*16 + quad*4;
                #pragma unroll
                for (int r = 0; r < 4; ++r) {
                    const int c = cbase + r;
                    const float v = acc[mt][ct][r] + zbias[c*VV + m] * zs;
                    obase[(size_t)c*TV] = v;
                    ps[mt*4 + r] += v;
                    pq[mt*4 + r] = fmaf(v, v, pq[mt*4 + r]);
                }
            }
        }
    }

    // reduce over the 16 lanes of each quad group (channel is lrow-invariant)
    #pragma unroll
    for (int off = 1; off < 16; off <<= 1) {
        #pragma unroll
        for (int i = 0; i < 12; ++i) {
            ps[i] += __shfl_xor(ps[i], off, 64);
            pq[i] += __shfl_xor(pq[i], off, 64);
        }
    }
    // plain LDS stores: slot nh; waves mh=0/1 cover channels 0..47 / 48..95
    if (lrow == 0) {
        #pragma unroll
        for (int i = 0; i < 12; ++i) {
            const int c = (mh*3 + (i >> 2))*16 + quad*4 + (i & 3);
            sh_stats[nh][c]      = ps[i];
            sh_stats[nh][96 + c] = pq[i];
        }
    }
    __syncthreads();
    if (tid < 192) {
        const int bucket = (px + b) & (NBUK - 1);
        atomicAdd(&stats[bucket*192 + tid], sh_stats[0][tid] + sh_stats[1][tid]);
    }
}

// ---------------------------------------------------------------------------
// k4: reduce the NBUK stat buckets for this channel (uniform scalar loads,
// L2-hit), then pure streaming normalize + relu, in place.
// ---------------------------------------------------------------------------
__global__ __launch_bounds__(256) void k4_norm(
    float* __restrict__ buf, const float* __restrict__ stats,
    const float* __restrict__ gamma, const float* __restrict__ beta)
{
    const int tid  = threadIdx.x;
    const int slab = blockIdx.x;              // b*COUT + c
    const int c    = slab % COUT;
    float s0 = 0.f, s1 = 0.f;
    #pragma unroll 8
    for (int u = 0; u < NBUK; ++u) {
        s0 += stats[u*192 + c];
        s1 += stats[u*192 + 96 + c];
    }
    const float invN = 1.0f / (float)(BB * TV);
    const float mean = s0 * invN;
    const float var  = s1 * invN - mean * mean;
    const float inv  = rsqrtf(var + BN_EPS);
    const float sc   = gamma[c] * inv;
    const float bi   = beta[c] - mean * sc;
    float4* p = (float4*)(buf + (size_t)slab * TV);
    for (int u = tid; u < TV/4; u += 256) {
        float4 v = p[u];
        v.x = fmaxf(fmaf(v.x, sc, bi), 0.0f);
        v.y = fmaxf(fmaf(v.y, sc, bi), 0.0f);
        v.z = fmaxf(fmaf(v.z, sc, bi), 0.0f);
        v.w = fmaxf(fmaf(v.w, sc, bi), 0.0f);
        p[u] = v;
    }
}

extern "C" void kernel_launch(void* const* d_in, const int* in_sizes, int n_in,
                              void* d_out, int out_size, void* d_ws, size_t ws_size,
                              hipStream_t stream) {
    const float* x      = (const float*)d_in[0];
    const float* A      = (const float*)d_in[1];
    const float* conv_w = (const float*)d_in[2];
    const float* conv_b = (const float*)d_in[3];
    const float* gamma  = (const float*)d_in[4];
    const float* beta   = (const float*)d_in[5];
    float* out = (float*)d_out;

    // ws layout: zbias(2400 f) | stats(NBUK*192 f) | Wflat (27648 bf16) | Bfr (3072 bf16)
    float* zbias = (float*)d_ws;
    float* stats = zbias + 2400;
    __hip_bfloat16* Wflat = (__hip_bfloat16*)(stats + NBUK*192);
    __hip_bfloat16* Bfr   = Wflat + (size_t)COUT * KK;

    // prep thread count: 27648 + 3072 + 2400 + NBUK*192 = 45,408 -> 178 blocks
    prep   <<<dim3(178),      dim3(256), 0, stream>>>(conv_w, A, conv_b, Wflat, Bfr, zbias, stats);
    fused  <<<dim3(TT/2, BB), dim3(256), 0, stream>>>(x, Wflat, Bfr, zbias, out, stats);
    k4_norm<<<dim3(BB*COUT),  dim3(256), 0, stream>>>(out, stats, gamma, beta);
}